// Round 1
// baseline (2254.674 us; speedup 1.0000x reference)
//
#include <hip/hip_runtime.h>

#define NUM_USERS 100000
#define NUM_ITEMS 50000
#define N_NODES   150000   // NUM_USERS + NUM_ITEMS
#define DIM       64
#define NUM_EDGES 2000000

// ---------------------------------------------------------------------------
// deg[col] += 1 for every edge
__global__ void degree_kernel(const int* __restrict__ col,
                              float* __restrict__ deg, int nE) {
    int stride = gridDim.x * blockDim.x;
    for (int e = blockIdx.x * blockDim.x + threadIdx.x; e < nE; e += stride)
        atomicAdd(&deg[col[e]], 1.0f);
}

// deg -> 1/sqrt(deg) in place (0 where deg==0)
__global__ void dinv_kernel(float* __restrict__ deg, int n) {
    int stride = gridDim.x * blockDim.x;
    for (int i = blockIdx.x * blockDim.x + threadIdx.x; i < n; i += stride) {
        float d = deg[i];
        deg[i] = (d > 0.0f) ? (1.0f / sqrtf(d)) : 0.0f;
    }
}

// out[col] += x[row] * dinv[row]*dinv[col]   (one wave per edge, lane = dim)
__global__ void scatter_kernel(const float* __restrict__ x,
                               const int* __restrict__ row,
                               const int* __restrict__ col,
                               const float* __restrict__ dinv,
                               float* __restrict__ out, int nE) {
    int lane = threadIdx.x & 63;
    int wid  = (blockIdx.x * blockDim.x + threadIdx.x) >> 6;
    int nW   = (gridDim.x * blockDim.x) >> 6;
    for (int e = wid; e < nE; e += nW) {
        int r = row[e];
        int c = col[e];
        float nm = dinv[r] * dinv[c];
        if (nm != 0.0f) {
            float v = x[(size_t)r * DIM + lane] * nm;
            atomicAdd(&out[(size_t)c * DIM + lane], v);
        }
    }
}

// o = (a + b + c) * (1/3)
__global__ void combine3_kernel(const float* __restrict__ a,
                                const float* __restrict__ b,
                                const float* __restrict__ c,
                                float* __restrict__ o, int n4) {
    const float4* A = (const float4*)a;
    const float4* B = (const float4*)b;
    const float4* C = (const float4*)c;
    float4* O = (float4*)o;
    const float s = 1.0f / 3.0f;
    int stride = gridDim.x * blockDim.x;
    for (int i = blockIdx.x * blockDim.x + threadIdx.x; i < n4; i += stride) {
        float4 x = A[i], y = B[i], z = C[i];
        float4 r;
        r.x = (x.x + y.x + z.x) * s;
        r.y = (x.y + y.y + z.y) * s;
        r.z = (x.z + y.z + z.z) * s;
        r.w = (x.w + y.w + z.w) * s;
        O[i] = r;
    }
}

// o = cart + (a + b + c) * (1/3)
__global__ void final_kernel(const float* __restrict__ cart,
                             const float* __restrict__ a,
                             const float* __restrict__ b,
                             const float* __restrict__ c,
                             float* __restrict__ o, int n4) {
    const float4* G = (const float4*)cart;
    const float4* A = (const float4*)a;
    const float4* B = (const float4*)b;
    const float4* C = (const float4*)c;
    float4* O = (float4*)o;
    const float s = 1.0f / 3.0f;
    int stride = gridDim.x * blockDim.x;
    for (int i = blockIdx.x * blockDim.x + threadIdx.x; i < n4; i += stride) {
        float4 g = G[i];
        float4 x = A[i], y = B[i], z = C[i];
        float4 r;
        r.x = g.x + (x.x + y.x + z.x) * s;
        r.y = g.y + (x.y + y.y + z.y) * s;
        r.z = g.z + (x.z + y.z + z.z) * s;
        r.w = g.w + (x.w + y.w + z.w) * s;
        O[i] = r;
    }
}

// Wt[k][j] = W[j][k] for both weight matrices (single block)
__global__ void transpose_w_kernel(const float* __restrict__ Wu,
                                   const float* __restrict__ Wi,
                                   float* __restrict__ WtU,
                                   float* __restrict__ WtI) {
    for (int t = threadIdx.x; t < DIM * DIM; t += blockDim.x) {
        int j = t >> 6, k = t & 63;
        WtU[k * DIM + j] = Wu[t];
        WtI[k * DIM + j] = Wi[t];
    }
}

// dst[i][j] = sum_k src[i][k] * Wt[k][j], Wt chosen per row (user vs item)
__global__ void matmul_kernel(const float* __restrict__ src,
                              const float* __restrict__ WtU,
                              const float* __restrict__ WtI,
                              float* __restrict__ dst) {
    __shared__ float rows[4][DIM];
    int lane = threadIdx.x & 63;
    int g = threadIdx.x >> 6;             // 0..3 : row within group of 4
    int totalGroups = N_NODES / 4;        // 37500
    for (int blk = blockIdx.x; blk < totalGroups; blk += gridDim.x) {
        int i = blk * 4 + g;
        rows[g][lane] = src[(size_t)i * DIM + lane];
        __syncthreads();
        const float* Wt = (i < NUM_USERS) ? WtU : WtI;
        float acc = 0.0f;
        #pragma unroll
        for (int k = 0; k < DIM; ++k)
            acc = fmaf(rows[g][k], Wt[k * DIM + lane], acc);   // LDS read is broadcast
        dst[(size_t)i * DIM + lane] = acc;
        __syncthreads();
    }
}

// ---------------------------------------------------------------------------
extern "C" void kernel_launch(void* const* d_in, const int* in_sizes, int n_in,
                              void* d_out, int out_size, void* d_ws, size_t ws_size,
                              hipStream_t stream) {
    const float* user_emb = (const float*)d_in[0];
    const float* item_emb = (const float*)d_in[1];
    const float* W_user   = (const float*)d_in[2];
    const float* W_item   = (const float*)d_in[3];
    const int*   ec       = (const int*)d_in[4];   // [2][NUM_EDGES]
    const int*   er       = (const int*)d_in[5];
    const int* cart_row = ec;
    const int* cart_col = ec + NUM_EDGES;
    const int* rent_row = er;
    const int* rent_col = er + NUM_EDGES;
    float* out = (float*)d_out;

    const size_t NV = (size_t)N_NODES * DIM;       // 9.6M floats
    float* ws   = (float*)d_ws;
    float* X    = ws;                 // node features / rent_init
    float* H1   = X    + NV;
    float* H2   = H1   + NV;
    float* CART = H2   + NV;
    float* DINV = CART + NV;
    float* WtU  = DINV + 150016;      // padded
    float* WtI  = WtU  + DIM * DIM;

    const int BLOCKS = 2048, THREADS = 256;

    // x0 = concat(user_emb, item_emb)
    hipMemcpyAsync(X, user_emb, (size_t)NUM_USERS * DIM * sizeof(float),
                   hipMemcpyDeviceToDevice, stream);
    hipMemcpyAsync(X + (size_t)NUM_USERS * DIM, item_emb,
                   (size_t)NUM_ITEMS * DIM * sizeof(float),
                   hipMemcpyDeviceToDevice, stream);
    transpose_w_kernel<<<1, 256, 0, stream>>>(W_user, W_item, WtU, WtI);

    // ---- behavior 1: cart ----
    hipMemsetAsync(DINV, 0, N_NODES * sizeof(float), stream);
    degree_kernel<<<BLOCKS, THREADS, 0, stream>>>(cart_col, DINV, NUM_EDGES);
    dinv_kernel<<<(N_NODES + 255) / 256, 256, 0, stream>>>(DINV, N_NODES);

    hipMemsetAsync(H1, 0, NV * sizeof(float), stream);
    scatter_kernel<<<BLOCKS, THREADS, 0, stream>>>(X, cart_row, cart_col, DINV, H1, NUM_EDGES);
    hipMemsetAsync(H2, 0, NV * sizeof(float), stream);
    scatter_kernel<<<BLOCKS, THREADS, 0, stream>>>(H1, cart_row, cart_col, DINV, H2, NUM_EDGES);
    combine3_kernel<<<BLOCKS, THREADS, 0, stream>>>(X, H1, H2, CART, (int)(NV / 4));

    // ---- projection: rent_init = cart @ W^T ----
    matmul_kernel<<<BLOCKS, THREADS, 0, stream>>>(CART, WtU, WtI, X);

    // ---- behavior 2: rent ----
    hipMemsetAsync(DINV, 0, N_NODES * sizeof(float), stream);
    degree_kernel<<<BLOCKS, THREADS, 0, stream>>>(rent_col, DINV, NUM_EDGES);
    dinv_kernel<<<(N_NODES + 255) / 256, 256, 0, stream>>>(DINV, N_NODES);

    hipMemsetAsync(H1, 0, NV * sizeof(float), stream);
    scatter_kernel<<<BLOCKS, THREADS, 0, stream>>>(X, rent_row, rent_col, DINV, H1, NUM_EDGES);
    hipMemsetAsync(H2, 0, NV * sizeof(float), stream);
    scatter_kernel<<<BLOCKS, THREADS, 0, stream>>>(H1, rent_row, rent_col, DINV, H2, NUM_EDGES);

    // out = cart + rent
    final_kernel<<<BLOCKS, THREADS, 0, stream>>>(CART, X, H1, H2, out, (int)(NV / 4));
}

// Round 4
// 999.517 us; speedup vs baseline: 2.2558x; 2.2558x over previous
//
#include <hip/hip_runtime.h>

#define NUM_USERS 100000
#define NUM_ITEMS 50000
#define N_NODES   150000   // NUM_USERS + NUM_ITEMS
#define DIM       64
#define NUM_EDGES 2000000

#define SCAN_THREADS 256
#define SCAN_ITEMS   8
#define SCAN_CHUNK   (SCAN_THREADS * SCAN_ITEMS)          // 2048
#define SCAN_NBLK    ((N_NODES + SCAN_CHUNK - 1) / SCAN_CHUNK)  // 74

// ---------------------------------------------------------------------------
// integer degree histogram over col
__global__ void deghist_kernel(const int* __restrict__ col,
                               int* __restrict__ deg, int nE) {
    int stride = gridDim.x * blockDim.x;
    for (int e = blockIdx.x * blockDim.x + threadIdx.x; e < nE; e += stride)
        atomicAdd(&deg[col[e]], 1);
}

// dinv[i] = deg>0 ? 1/sqrt(deg) : 0
__global__ void dinv_kernel(const int* __restrict__ deg,
                            float* __restrict__ dinv, int n) {
    int stride = gridDim.x * blockDim.x;
    for (int i = blockIdx.x * blockDim.x + threadIdx.x; i < n; i += stride) {
        float d = (float)deg[i];
        dinv[i] = (d > 0.0f) ? (1.0f / sqrtf(d)) : 0.0f;
    }
}

// ---- exclusive scan of deg -> col_ptr (3 kernels) ----
__global__ void scanA_kernel(const int* __restrict__ deg,
                             int* __restrict__ colptr,
                             int* __restrict__ bsum) {
    __shared__ int s[SCAN_THREADS];
    int t = threadIdx.x;
    int base = blockIdx.x * SCAN_CHUNK + t * SCAN_ITEMS;
    int items[SCAN_ITEMS];
    int mysum = 0;
    #pragma unroll
    for (int j = 0; j < SCAN_ITEMS; ++j) {
        int idx = base + j;
        items[j] = (idx < N_NODES) ? deg[idx] : 0;
        mysum += items[j];
    }
    s[t] = mysum;
    __syncthreads();
    // Hillis-Steele inclusive scan
    for (int off = 1; off < SCAN_THREADS; off <<= 1) {
        int v = (t >= off) ? s[t - off] : 0;
        __syncthreads();
        s[t] += v;
        __syncthreads();
    }
    int excl = s[t] - mysum;                 // exclusive prefix for this thread
    if (t == SCAN_THREADS - 1) bsum[blockIdx.x] = s[t];
    int run = excl;
    #pragma unroll
    for (int j = 0; j < SCAN_ITEMS; ++j) {
        int idx = base + j;
        if (idx < N_NODES) colptr[idx] = run;   // local (per-block) exclusive
        run += items[j];
    }
}

__global__ void scanB_kernel(int* __restrict__ bsum,
                             int* __restrict__ boff,
                             int* __restrict__ colptr) {
    if (threadIdx.x == 0) {
        int run = 0;
        for (int b = 0; b < SCAN_NBLK; ++b) {
            boff[b] = run;
            run += bsum[b];
        }
        colptr[N_NODES] = run;     // == NUM_EDGES
    }
}

__global__ void scanC_kernel(int* __restrict__ colptr,
                             int* __restrict__ cursor,
                             const int* __restrict__ boff) {
    int t = threadIdx.x;
    int off = boff[blockIdx.x];
    int base = blockIdx.x * SCAN_CHUNK + t * SCAN_ITEMS;
    #pragma unroll
    for (int j = 0; j < SCAN_ITEMS; ++j) {
        int idx = base + j;
        if (idx < N_NODES) {
            int v = colptr[idx] + off;
            colptr[idx] = v;
            cursor[idx] = v;
        }
    }
}

// bucket edges by col: edata[p] = {row, norm}
__global__ void edgescatter_kernel(const int* __restrict__ row,
                                   const int* __restrict__ col,
                                   const float* __restrict__ dinv,
                                   int* __restrict__ cursor,
                                   int2* __restrict__ edata, int nE) {
    int stride = gridDim.x * blockDim.x;
    for (int e = blockIdx.x * blockDim.x + threadIdx.x; e < nE; e += stride) {
        int r = row[e];
        int c = col[e];
        int p = atomicAdd(&cursor[c], 1);
        float nm = dinv[r] * dinv[c];
        edata[p] = make_int2(r, __float_as_int(nm));
    }
}

// ---------------------------------------------------------------------------
// CSR gather conv. One wave per node, lane = dim.
// MODE 0: out[node] = sum
// MODE 1: out[node] = (a0 + a1 + sum) / 3                  (combine after layer 2)
// MODE 2: out[node] = a2 + (a0 + a1 + sum) / 3             (final add)
template <int MODE>
__global__ void conv_kernel(const float* __restrict__ xin,
                            const int* __restrict__ colptr,
                            const int2* __restrict__ edata,
                            const float* __restrict__ a0,
                            const float* __restrict__ a1,
                            const float* __restrict__ a2,
                            float* __restrict__ out) {
    int lane = threadIdx.x & 63;
    int node = (blockIdx.x * blockDim.x + threadIdx.x) >> 6;
    if (node >= N_NODES) return;
    int s = colptr[node];
    int t = colptr[node + 1];
    float acc = 0.0f;
    #pragma unroll 4
    for (int e = s; e < t; ++e) {
        int2 ed = edata[e];                                   // broadcast load
        acc = fmaf(__int_as_float(ed.y), xin[(size_t)ed.x * DIM + lane], acc);
    }
    size_t o = (size_t)node * DIM + lane;
    if (MODE == 0) {
        out[o] = acc;
    } else if (MODE == 1) {
        out[o] = (a0[o] + a1[o] + acc) * (1.0f / 3.0f);
    } else {
        out[o] = a2[o] + (a0[o] + a1[o] + acc) * (1.0f / 3.0f);
    }
}

// Wt[k][j] = W[j][k] for both weight matrices (single block)
__global__ void transpose_w_kernel(const float* __restrict__ Wu,
                                   const float* __restrict__ Wi,
                                   float* __restrict__ WtU,
                                   float* __restrict__ WtI) {
    for (int t = threadIdx.x; t < DIM * DIM; t += blockDim.x) {
        int j = t >> 6, k = t & 63;
        WtU[k * DIM + j] = Wu[t];
        WtI[k * DIM + j] = Wi[t];
    }
}

// dst[i][j] = sum_k src[i][k] * Wt[k][j], Wt chosen per row (user vs item)
__global__ void matmul_kernel(const float* __restrict__ src,
                              const float* __restrict__ WtU,
                              const float* __restrict__ WtI,
                              float* __restrict__ dst) {
    __shared__ float rows[4][DIM];
    int lane = threadIdx.x & 63;
    int g = threadIdx.x >> 6;             // 0..3 : row within group of 4
    int totalGroups = N_NODES / 4;        // 37500
    for (int blk = blockIdx.x; blk < totalGroups; blk += gridDim.x) {
        int i = blk * 4 + g;
        rows[g][lane] = src[(size_t)i * DIM + lane];
        __syncthreads();
        const float* Wt = (i < NUM_USERS) ? WtU : WtI;
        float acc = 0.0f;
        #pragma unroll
        for (int k = 0; k < DIM; ++k)
            acc = fmaf(rows[g][k], Wt[k * DIM + lane], acc);   // LDS broadcast
        dst[(size_t)i * DIM + lane] = acc;
        __syncthreads();
    }
}

// ---------------------------------------------------------------------------
extern "C" void kernel_launch(void* const* d_in, const int* in_sizes, int n_in,
                              void* d_out, int out_size, void* d_ws, size_t ws_size,
                              hipStream_t stream) {
    const float* user_emb = (const float*)d_in[0];
    const float* item_emb = (const float*)d_in[1];
    const float* W_user   = (const float*)d_in[2];
    const float* W_item   = (const float*)d_in[3];
    const int*   ec       = (const int*)d_in[4];   // [2][NUM_EDGES]
    const int*   er       = (const int*)d_in[5];
    const int* cart_row = ec;
    const int* cart_col = ec + NUM_EDGES;
    const int* rent_row = er;
    const int* rent_col = er + NUM_EDGES;
    float* out = (float*)d_out;

    const size_t NV = (size_t)N_NODES * DIM;       // 9.6M floats
    float* ws    = (float*)d_ws;
    float* X     = ws;                  // node features / rent_init
    float* H1    = X    + NV;
    float* CART  = H1   + NV;
    float* DINV  = CART + NV;
    int*   DEG   = (int*)(DINV + 150016);
    int*   CPTR  = DEG  + 150016;
    int*   CURS  = CPTR + 150016;
    int*   BSUM  = CURS + 150016;
    int*   BOFF  = BSUM + 128;
    float* WtU   = (float*)(BOFF + 128);
    float* WtI   = WtU + DIM * DIM;
    int2*  EDATA = (int2*)(WtI + DIM * DIM);       // 2M int2 = 16 MB

    const int BLOCKS = 2048, THREADS = 256;
    const int CONV_BLOCKS = (N_NODES + 3) / 4;     // 4 waves (nodes) per block

    // x0 = concat(user_emb, item_emb)
    hipMemcpyAsync(X, user_emb, (size_t)NUM_USERS * DIM * sizeof(float),
                   hipMemcpyDeviceToDevice, stream);
    hipMemcpyAsync(X + (size_t)NUM_USERS * DIM, item_emb,
                   (size_t)NUM_ITEMS * DIM * sizeof(float),
                   hipMemcpyDeviceToDevice, stream);
    transpose_w_kernel<<<1, 256, 0, stream>>>(W_user, W_item, WtU, WtI);

    // ================= behavior 1: cart =================
    hipMemsetAsync(DEG, 0, N_NODES * sizeof(int), stream);
    deghist_kernel<<<BLOCKS, THREADS, 0, stream>>>(cart_col, DEG, NUM_EDGES);
    dinv_kernel<<<(N_NODES + 255) / 256, 256, 0, stream>>>(DEG, DINV, N_NODES);
    scanA_kernel<<<SCAN_NBLK, SCAN_THREADS, 0, stream>>>(DEG, CPTR, BSUM);
    scanB_kernel<<<1, 64, 0, stream>>>(BSUM, BOFF, CPTR);
    scanC_kernel<<<SCAN_NBLK, SCAN_THREADS, 0, stream>>>(CPTR, CURS, BOFF);
    edgescatter_kernel<<<BLOCKS, THREADS, 0, stream>>>(cart_row, cart_col, DINV,
                                                       CURS, EDATA, NUM_EDGES);

    // layer 1: H1 = conv(X); layer 2 fused with combine: CART = (X+H1+conv(H1))/3
    conv_kernel<0><<<CONV_BLOCKS, 256, 0, stream>>>(X, CPTR, EDATA,
                                                    nullptr, nullptr, nullptr, H1);
    conv_kernel<1><<<CONV_BLOCKS, 256, 0, stream>>>(H1, CPTR, EDATA,
                                                    X, H1, nullptr, CART);

    // ---- projection: X = CART @ W^T (per-row user/item) ----
    matmul_kernel<<<BLOCKS, THREADS, 0, stream>>>(CART, WtU, WtI, X);

    // ================= behavior 2: rent =================
    hipMemsetAsync(DEG, 0, N_NODES * sizeof(int), stream);
    deghist_kernel<<<BLOCKS, THREADS, 0, stream>>>(rent_col, DEG, NUM_EDGES);
    dinv_kernel<<<(N_NODES + 255) / 256, 256, 0, stream>>>(DEG, DINV, N_NODES);
    scanA_kernel<<<SCAN_NBLK, SCAN_THREADS, 0, stream>>>(DEG, CPTR, BSUM);
    scanB_kernel<<<1, 64, 0, stream>>>(BSUM, BOFF, CPTR);
    scanC_kernel<<<SCAN_NBLK, SCAN_THREADS, 0, stream>>>(CPTR, CURS, BOFF);
    edgescatter_kernel<<<BLOCKS, THREADS, 0, stream>>>(rent_row, rent_col, DINV,
                                                       CURS, EDATA, NUM_EDGES);

    // layer 1: H1 = conv(X); layer 2 fused with final: out = CART + (X+H1+conv(H1))/3
    conv_kernel<0><<<CONV_BLOCKS, 256, 0, stream>>>(X, CPTR, EDATA,
                                                    nullptr, nullptr, nullptr, H1);
    conv_kernel<2><<<CONV_BLOCKS, 256, 0, stream>>>(H1, CPTR, EDATA,
                                                    X, H1, CART, out);
}